// Round 2
// baseline (272.499 us; speedup 1.0000x reference)
//
#include <hip/hip_runtime.h>

// Reference numpy/jnp math is UNFUSED IEEE f32 — disable FMA contraction so
// the catastrophically-cancelled det (compared against EPS=1e-7) and the
// 1/det-scaled shifts are bit-identical to the reference.
#pragma clang fp contract(off)

// Problem constants (from setup_inputs): B=2, C=4, D=6, H=512, W=512, f32.
constexpr int B_ = 2, C_ = 4, D_ = 6, H_ = 512, W_ = 512;
constexpr int HW_  = H_ * W_;        // 262144
constexpr int DHW_ = D_ * HW_;       // 1572864
constexpr int BC_  = B_ * C_;        // 8
constexpr int TOT_ = BC_ * DHW_;     // 12582912

#define EPS_ 1e-7f
#define MAX_SHIFT_ 0.6f
#define BONUS_ 10.0f
#define N_ITERS_ 5

// 3x3x3 quadratic-fit Cramer solve at interior voxel; p points at the center.
// Op ordering mirrors the reference exactly (f32, no contraction).
__device__ __forceinline__ void solve3(const float* __restrict__ p,
                                       float& sx, float& sy, float& ss,
                                       float& gds, bool& sol)
{
    #pragma clang fp contract(off)
    float c    = p[0];
    float xp   = p[1],          xm   = p[-1];
    float yp   = p[W_],         ym   = p[-W_];
    float spv  = p[HW_],        smv  = p[-HW_];
    float xpyp = p[W_ + 1],     xmyp = p[W_ - 1];
    float xpym = p[-W_ + 1],    xmym = p[-W_ - 1];
    float xpsp = p[HW_ + 1],    xmsp = p[HW_ - 1];
    float xpsm = p[-HW_ + 1],   xmsm = p[-HW_ - 1];
    float ypsp = p[HW_ + W_],   ymsp = p[HW_ - W_];
    float ypsm = p[-HW_ + W_],  ymsm = p[-HW_ - W_];

    float gx = 0.5f * (xp - xm);
    float gy = 0.5f * (yp - ym);
    float gs = 0.5f * (spv - smv);
    float dxx = xp - 2.0f * c + xm;
    float dyy = yp - 2.0f * c + ym;
    float dss = spv - 2.0f * c + smv;
    float dxy = 0.25f * (xpyp - xmyp - xpym + xmym);
    float dxs = 0.25f * (xpsp - xmsp - xpsm + xmsm);
    float dys = 0.25f * (ypsp - ymsp - ypsm + ymsm);

    float cf00 = dyy * dss - dys * dys;
    float cf01 = dxy * dss - dys * dxs;
    float cf02 = dxy * dys - dyy * dxs;
    float det  = dxx * cf00 - dxy * cf01 + dxs * cf02;
    sol = fabsf(det) > EPS_;
    float sd = sol ? det : 1.0f;
    float r0 = -gx, r1 = -gy, r2 = -gs;
    sx = (r0 * cf00 - dxy * (r1 * dss - dys * r2) + dxs * (r1 * dys - dyy * r2)) / sd;
    sy = (dxx * (r1 * dss - dys * r2) - r0 * cf01 + dxs * (dxy * r2 - r1 * dxs)) / sd;
    ss = (dxx * (dyy * r2 - r1 * dys) - dxy * (dxy * r2 - r1 * dxs) + r0 * cf02) / sd;
    gds = gx * sx + gy * sy + gs * ss;
}

__global__ __launch_bounds__(256)
void AdaptiveQuadInterp3d_kernel(const float* __restrict__ x,
                                 const int* __restrict__ mask,
                                 float* __restrict__ out)
{
    #pragma clang fp contract(off)
    int idx = blockIdx.x * 256 + threadIdx.x;
    if (idx >= TOT_) return;

    int w  = idx & (W_ - 1);
    int h  = (idx >> 9) & (H_ - 1);
    int t  = idx >> 18;          // bc*D + d   (since HW = 2^18)
    int d  = t % D_;
    int bc = t / D_;
    int sp = idx - bc * DHW_;    // d*HW + h*W + w

    float xc = x[idx];
    bool  m  = mask[idx] != 0;   // bool inputs are materialized as int32

    float yv, cs, cx, cy;

    if (!m) {
        yv = xc;
        cs = (float)d;
        cx = (float)w;
        cy = (float)h;
    } else {
        const float* xb = x + bc * DHW_;
        int dd = 0, dh = 0, dwo = 0;
        bool valid = true;
        float shx = 0.0f, shy = 0.0f, shs = 0.0f, gk = 0.0f;

        #pragma unroll 1
        for (int it = 0; it < N_ITERS_; ++it) {
            int di = min(max(d + dd, 1), D_ - 2);
            int hi = min(max(h + dh, 1), H_ - 2);
            int wi = min(max(w + dwo, 1), W_ - 2);
            const float* p = xb + di * HW_ + hi * W_ + wi;

            float sx, sy, ssv, gds; bool sol;
            solve3(p, sx, sy, ssv, gds, sol);

            valid = valid && sol;
            float vf = valid ? 1.0f : 0.0f;
            shx = sx * vf;
            shy = sy * vf;
            shs = ssv * vf;
            gk  = gds * vf;

            int stx = (shx > MAX_SHIFT_) ? 1 : ((shx < -MAX_SHIFT_) ? -1 : 0);
            int sty = (shy > MAX_SHIFT_) ? 1 : ((shy < -MAX_SHIFT_) ? -1 : 0);
            int sts = (shs > MAX_SHIFT_) ? 1 : ((shs < -MAX_SHIFT_) ? -1 : 0);
            dwo += stx;
            dh  += sty;
            dd  += sts;
            valid = valid && (abs(dd) <= 1) && (abs(dh) <= 1) && (abs(dwo) <= 1);
        }

        int di = min(max(d + dd, 1), D_ - 2);
        int hi = min(max(h + dh, 1), H_ - 2);
        int wi = min(max(w + dwo, 1), W_ - 2);
        float cur = xb[di * HW_ + hi * W_ + wi];

        float refined = valid ? (cur + 0.5f * gk) : xc;
        yv = refined + BONUS_;                 // nms_mask true here
        cs = valid ? ((float)(d + dd) + shs) : (float)d;
        cx = valid ? ((float)(w + dwo) + shx) : (float)w;
        cy = valid ? ((float)(h + dh) + shy) : (float)h;
    }

    // coords_max: (B, C, 3, D, H, W), order [cs, cx, cy]; then y_max (B,C,D,H,W)
    out[(bc * 3 + 0) * DHW_ + sp] = cs;
    out[(bc * 3 + 1) * DHW_ + sp] = cx;
    out[(bc * 3 + 2) * DHW_ + sp] = cy;
    out[BC_ * 3 * DHW_ + idx]     = yv;
}

extern "C" void kernel_launch(void* const* d_in, const int* in_sizes, int n_in,
                              void* d_out, int out_size, void* d_ws, size_t ws_size,
                              hipStream_t stream) {
    const float* x    = (const float*)d_in[0];
    const int*   mask = (const int*)d_in[1];
    float*       out  = (float*)d_out;

    int blocks = (TOT_ + 255) / 256;
    AdaptiveQuadInterp3d_kernel<<<blocks, 256, 0, stream>>>(x, mask, out);
}